// Round 4
// baseline (69.736 us; speedup 1.0000x reference)
//
#include <hip/hip_runtime.h>
#include <hip/hip_cooperative_groups.h>
#include <cstdint>

namespace cg = cooperative_groups;

// out[b][o] = (luts[o][addr(b,o)] > 0) where addr = 6 bits of x gathered by mapping[o].
// B=512, I=8192, O=4096, N=6, T=64.
//
// Bit-sliced formulation (see round 2/3): each o is a 6-input LUT with 64-bit
// truth table tt[o] = sign bits of luts[o][:]. x packs column-major into
// 32-deep bit-planes xT[cp][i]; one lane evaluates 32 batch rows at once via
// a Shannon mux tree over 32-bit planes.
//
// Round 4: fuse pack + main into ONE cooperative kernel (grid sync between
// phases) to eliminate one graph dispatch + inter-kernel drain. Phase bodies
// identical to round 3. 272 blocks x 256 thr = 1088 wave-tasks = 1024 x-pack
// + 64 lut-pack (phase 1) and covers 1024 main tasks (phase 2).

constexpr int B_ = 512;
constexpr int I_ = 8192;
constexpr int O_ = 4096;
constexpr int T_ = 64;

constexpr int CCH = B_ / 32;             // 16 bit-plane chunks of 32 batch rows
constexpr int XTASKS = CCH * (I_ / 128); // 1024 x-pack wave-tasks (32 x 128 tiles)
constexpr int LTASKS = O_ / 64;          // 64 lut-pack wave-tasks
constexpr int MTASKS = CCH * (O_ / 64);  // 1024 main wave-tasks
constexpr int NBLK = (XTASKS + LTASKS) / 4;  // 272 blocks

__global__ __launch_bounds__(256)
void LUT_fused_kernel(const float* __restrict__ x,
                      const int* __restrict__ mapping,
                      const float* __restrict__ luts,
                      uint32_t* __restrict__ xT,
                      uint2* __restrict__ lutsign,
                      float* __restrict__ out)
{
    const int wtask = blockIdx.x * 4 + (threadIdx.x >> 6);
    const int lane  = threadIdx.x & 63;

    // ================= Phase 1: pack =================
    if (wtask < XTASKS) {
        // ---- pack a 32(b) x 128(i) tile of x into 128 column words ----
        const int cp = wtask >> 6;         // [0,16) plane chunk
        const int ig = wtask & 63;         // [0,64) column group of 128
        const int b0 = cp * 32, i0 = ig * 128;

        const uint64_t* xr = (const uint64_t*)(x + (size_t)b0 * I_ + i0) + lane;
        uint32_t wA = 0, wB = 0;
        #pragma unroll
        for (int r = 0; r < 32; ++r) {
            const uint64_t u = __builtin_nontemporal_load(xr + (size_t)r * (I_ / 2));
            // x is exactly 0.0f (0x00000000) or 1.0f (0x3F800000): bit29 = value
            wA |= (uint32_t)((u >> 29) & 1ull) << r;
            wB |= (uint32_t)((u >> 61) & 1ull) << r;
        }
        const uint64_t w = ((uint64_t)wB << 32) | (uint64_t)wA;
        *(uint64_t*)(xT + (size_t)cp * I_ + i0 + 2 * lane) = w;  // keep L2-resident
    } else {
        // ---- pack sign bits of lut row o into a 64-bit truth table ----
        const int o = (wtask - XTASKS) * 64 + lane;
        const float4* lr = (const float4*)(luts + (size_t)o * T_);
        uint32_t t0 = 0, t1 = 0;
        #pragma unroll
        for (int q = 0; q < 8; ++q) {
            const float4 f = lr[q];
            const int j = 4 * q;
            t0 |= (f.x > 0.0f ? 1u : 0u) << j;
            t0 |= (f.y > 0.0f ? 1u : 0u) << (j + 1);
            t0 |= (f.z > 0.0f ? 1u : 0u) << (j + 2);
            t0 |= (f.w > 0.0f ? 1u : 0u) << (j + 3);
        }
        #pragma unroll
        for (int q = 8; q < 16; ++q) {
            const float4 f = lr[q];
            const int j = 4 * q - 32;
            t1 |= (f.x > 0.0f ? 1u : 0u) << j;
            t1 |= (f.y > 0.0f ? 1u : 0u) << (j + 1);
            t1 |= (f.z > 0.0f ? 1u : 0u) << (j + 2);
            t1 |= (f.w > 0.0f ? 1u : 0u) << (j + 3);
        }
        lutsign[o] = make_uint2(t0, t1);
    }

    __threadfence();              // agent-scope: drain xT/lutsign stores (cross-XCD)
    cg::this_grid().sync();

    // ================= Phase 2: main =================
    if (wtask < MTASKS) {
        const int cp = wtask >> 6;             // [0,16)
        const int og = wtask & 63;
        const int o  = og * 64 + lane;         // this lane's output column

        // mapping row: 6 ints, 8 B aligned (o*6 even) -> 3 x int2 loads
        const int2* mp = (const int2*)(mapping + o * 6);
        const int2 m01 = mp[0], m23 = mp[1], m45 = mp[2];

        const uint32_t* xs = xT + (size_t)cp * I_;  // wave-uniform 32 KB slice (L2)
        const uint32_t w0 = xs[m01.x], w1 = xs[m01.y];
        const uint32_t w2 = xs[m23.x], w3 = xs[m23.y];
        const uint32_t w4 = xs[m45.x], w5 = xs[m45.y];

        const uint2 tt = lutsign[o];
        const uint32_t ttl = tt.x, tth = tt.y;

        // Shannon mux tree: res bit r = tt[addr(b = cp*32+r)]
        uint32_t p[32];
        #pragma unroll
        for (int j = 0; j < 32; ++j) {         // level 1: consume w0 + tt bits
            const uint32_t half = (j < 16) ? ttl : tth;
            const int sh = (2 * j) & 31;
            const uint32_t em = 0u - ((half >> sh) & 1u);
            const uint32_t om = 0u - ((half >> (sh + 1)) & 1u);
            p[j] = (om & w0) | (em & ~w0);     // -> v_bfi_b32
        }
        #pragma unroll
        for (int j = 0; j < 16; ++j) p[j] = (p[2*j+1] & w1) | (p[2*j] & ~w1);
        #pragma unroll
        for (int j = 0; j < 8;  ++j) p[j] = (p[2*j+1] & w2) | (p[2*j] & ~w2);
        #pragma unroll
        for (int j = 0; j < 4;  ++j) p[j] = (p[2*j+1] & w3) | (p[2*j] & ~w3);
        p[0] = (p[1] & w4) | (p[0] & ~w4);
        p[1] = (p[3] & w4) | (p[2] & ~w4);
        const uint32_t res = (p[1] & w5) | (p[0] & ~w5);

        // res bit r is the output for batch row b = cp*32 + r, column o.
        #pragma unroll
        for (int r = 0; r < 32; ++r) {
            const float v = (float)((res >> r) & 1u);
            __builtin_nontemporal_store(v, out + (size_t)(cp * 32 + r) * O_ + o);
        }
    }
}

extern "C" void kernel_launch(void* const* d_in, const int* in_sizes, int n_in,
                              void* d_out, int out_size, void* d_ws, size_t ws_size,
                              hipStream_t stream) {
    const float* x       = (const float*)d_in[0];
    const int*   mapping = (const int*)d_in[1];
    const float* luts    = (const float*)d_in[2];
    float*       out     = (float*)d_out;

    uint32_t* xT = (uint32_t*)d_ws;                                // 512 KB
    uint2* lutsign = (uint2*)((char*)d_ws + (size_t)CCH * I_ * 4); // +32 KB

    void* args[6] = { (void*)&x, (void*)&mapping, (void*)&luts,
                      (void*)&xT, (void*)&lutsign, (void*)&out };
    hipLaunchCooperativeKernel((void*)LUT_fused_kernel,
                               dim3(NBLK), dim3(256), args, 0, stream);
}

// Round 5
// 13.689 us; speedup vs baseline: 5.0944x; 5.0944x over previous
//
#include <hip/hip_runtime.h>
#include <cstdint>

// out[b][o] = (luts[o][addr(b,o)] > 0) where addr = 6 bits of x gathered by mapping[o].
// B=512, I=8192, O=4096, N=6, T=64.
//
// Bit-sliced formulation: each o is a 6-input LUT with 64-bit truth table
// tt[o] = sign bits of luts[o][0..63]. Pack x column-major into 32-deep
// bit-planes xT[cp][i] (bit r = x[cp*32+r][i] != 0); then one lane evaluates
// 32 batch rows at once via a Shannon mux tree over 32-bit planes.
//
// Pack kernel (no ballot needed): lane l loads x[b0+r][i0+2l..2l+1] per row
// (coalesced 512 B/wave-instr, nontemporal) and builds its two column words
// directly: wd |= bit29(u) << r  (x is exactly 0.0f/1.0f -> bit29 test).
// Truth tables: per-lane float4 scan of one 256 B lut row.
// Main kernel: 6 gathers from a wave-uniform 32 KB L2-resident slice + tt
// load + ~110 VALU -> 32 outputs, written as nontemporal coalesced stores.
//
// R4 post-mortem: cooperative-launch fusion of these two kernels regressed
// 13.6 -> 69.7 us (cg grid.sync ~55 us on 272 blocks; software barrier with
// system-scope fences across 8 non-coherent XCD L2s). The ~9 us residual in
// dur_us is fixed harness overhead, not dispatch overhead. Two plain
// dispatches is the right structure.

constexpr int B_ = 512;
constexpr int I_ = 8192;
constexpr int O_ = 4096;
constexpr int T_ = 64;

constexpr int CCH = B_ / 32;            // 16 bit-plane chunks of 32 batch rows
constexpr int XTASKS = CCH * (I_ / 128); // 1024 pack wave-tasks (32 x 128 tiles)
constexpr int LTASKS = O_ / 64;          // 64 lut-pack wave-tasks

__global__ __launch_bounds__(256)
void LUT_pack_kernel(const float* __restrict__ x,
                     const float* __restrict__ luts,
                     uint32_t* __restrict__ xT,
                     uint2* __restrict__ lutsign)
{
    const int task = blockIdx.x * 4 + (threadIdx.x >> 6);
    const int lane = threadIdx.x & 63;

    if (task < XTASKS) {
        // ---- pack a 32(b) x 128(i) tile of x into 128 column words ----
        const int cp = task >> 6;          // [0,16) plane chunk
        const int ig = task & 63;          // [0,64) column group of 128
        const int b0 = cp * 32, i0 = ig * 128;

        const uint64_t* xr = (const uint64_t*)(x + (size_t)b0 * I_ + i0) + lane;
        uint32_t wA = 0, wB = 0;
        #pragma unroll
        for (int r = 0; r < 32; ++r) {
            const uint64_t u = __builtin_nontemporal_load(xr + (size_t)r * (I_ / 2));
            // x is exactly 0.0f (0x00000000) or 1.0f (0x3F800000): bit29 = value
            wA |= (uint32_t)((u >> 29) & 1ull) << r;
            wB |= (uint32_t)((u >> 61) & 1ull) << r;
        }
        // regular store: xT must stay L2-resident for the main kernel
        const uint64_t w = ((uint64_t)wB << 32) | (uint64_t)wA;
        *(uint64_t*)(xT + (size_t)cp * I_ + i0 + 2 * lane) = w;
    } else {
        // ---- pack sign bits of lut row o into a 64-bit truth table ----
        const int o = (task - XTASKS) * 64 + lane;
        const float4* lr = (const float4*)(luts + (size_t)o * T_);
        uint32_t t0 = 0, t1 = 0;
        #pragma unroll
        for (int q = 0; q < 8; ++q) {
            const float4 f = lr[q];
            const int j = 4 * q;
            t0 |= (f.x > 0.0f ? 1u : 0u) << j;
            t0 |= (f.y > 0.0f ? 1u : 0u) << (j + 1);
            t0 |= (f.z > 0.0f ? 1u : 0u) << (j + 2);
            t0 |= (f.w > 0.0f ? 1u : 0u) << (j + 3);
        }
        #pragma unroll
        for (int q = 8; q < 16; ++q) {
            const float4 f = lr[q];
            const int j = 4 * q - 32;
            t1 |= (f.x > 0.0f ? 1u : 0u) << j;
            t1 |= (f.y > 0.0f ? 1u : 0u) << (j + 1);
            t1 |= (f.z > 0.0f ? 1u : 0u) << (j + 2);
            t1 |= (f.w > 0.0f ? 1u : 0u) << (j + 3);
        }
        lutsign[o] = make_uint2(t0, t1);   // coalesced 512 B store
    }
}

__global__ __launch_bounds__(256)
void LUT_main_kernel(const int* __restrict__ mapping,
                     const uint32_t* __restrict__ xT,
                     const uint2* __restrict__ lutsign,
                     float* __restrict__ out)
{
    const int task = blockIdx.x * 4 + (threadIdx.x >> 6);  // [0,1024)
    const int lane = threadIdx.x & 63;
    const int cp = task >> 6;              // [0,16) — all 4 waves of a block
    const int og = task & 63;              //          share one 32 KB slice
    const int o  = og * 64 + lane;         // this lane's output column

    // mapping row: 6 ints, 8 B aligned (o*6 even) -> 3 x int2 loads
    const int2* mp = (const int2*)(mapping + o * 6);
    const int2 m01 = mp[0], m23 = mp[1], m45 = mp[2];

    const uint32_t* xs = xT + (size_t)cp * I_;  // wave-uniform 32 KB slice (L2)
    const uint32_t w0 = xs[m01.x], w1 = xs[m01.y];
    const uint32_t w2 = xs[m23.x], w3 = xs[m23.y];
    const uint32_t w4 = xs[m45.x], w5 = xs[m45.y];

    const uint2 tt = lutsign[o];
    const uint32_t ttl = tt.x, tth = tt.y;

    // Shannon mux tree: res bit r = tt[addr(b = cp*32+r)]
    uint32_t p[32];
    #pragma unroll
    for (int j = 0; j < 32; ++j) {         // level 1: consume w0 + tt bits
        const uint32_t half = (j < 16) ? ttl : tth;
        const int sh = (2 * j) & 31;
        const uint32_t em = 0u - ((half >> sh) & 1u);
        const uint32_t om = 0u - ((half >> (sh + 1)) & 1u);
        p[j] = (om & w0) | (em & ~w0);     // -> v_bfi_b32
    }
    #pragma unroll
    for (int j = 0; j < 16; ++j) p[j] = (p[2*j+1] & w1) | (p[2*j] & ~w1);
    #pragma unroll
    for (int j = 0; j < 8;  ++j) p[j] = (p[2*j+1] & w2) | (p[2*j] & ~w2);
    #pragma unroll
    for (int j = 0; j < 4;  ++j) p[j] = (p[2*j+1] & w3) | (p[2*j] & ~w3);
    p[0] = (p[1] & w4) | (p[0] & ~w4);
    p[1] = (p[3] & w4) | (p[2] & ~w4);
    const uint32_t res = (p[1] & w5) | (p[0] & ~w5);

    // res bit r is the output for batch row b = cp*32 + r, column o.
    #pragma unroll
    for (int r = 0; r < 32; ++r) {
        const float v = (float)((res >> r) & 1u);
        __builtin_nontemporal_store(v, out + (size_t)(cp * 32 + r) * O_ + o);
    }
}

extern "C" void kernel_launch(void* const* d_in, const int* in_sizes, int n_in,
                              void* d_out, int out_size, void* d_ws, size_t ws_size,
                              hipStream_t stream) {
    const float* x       = (const float*)d_in[0];
    const int*   mapping = (const int*)d_in[1];
    const float* luts    = (const float*)d_in[2];
    float*       out     = (float*)d_out;

    uint32_t* xT = (uint32_t*)d_ws;                             // 512 KB
    uint2* lutsign = (uint2*)((char*)d_ws + (size_t)CCH * I_ * 4); // +32 KB

    LUT_pack_kernel<<<(XTASKS + LTASKS) / 4, 256, 0, stream>>>(x, luts, xT, lutsign);
    LUT_main_kernel<<<(CCH * (O_ / 64)) / 4, 256, 0, stream>>>(mapping, xT, lutsign, out);
}